// Round 7
// baseline (18.397 us; speedup 1.0000x reference)
//
#include <hip/hip_runtime.h>

// CRF-RNN 1-D message passing. B=16, N=100000, K=11 (HALF=5), 5 iterations.
// 4 independent wave-tiles per 256-thread workgroup (cuts WG count 4x for
// full resident occupancy). Per wave: thread owns G=4 consecutive positions;
// zero LDS, zero barriers — feature halo, weight symmetry, and q-halo all via
// width-64 shuffles. Each unique Gaussian weight computed by exactly one lane.
// Edge tiles (2 per image) take a scalar clamped path with masks.

constexpr int BLK   = 256;           // 4 waves
constexpr int WPB   = 4;             // wave-tiles per workgroup
constexpr int G     = 4;             // positions per thread
constexpr int E     = 64 * G;        // 256 ext positions per wave-tile
constexpr int HL    = 28;            // halo each side (erosion-safe: 8 + 4*5 = 28)
constexpr int C     = E - 2 * HL;    // 200 outputs per tile (N = 500*200 exact)
constexpr int NITER = 5;
constexpr int N_    = 100000;
constexpr int CPB   = (N_ + C - 1) / C;  // 500 chunks per image
constexpr float EPS = 1e-8f;

__device__ __forceinline__ float frcp(float x) { return __builtin_amdgcn_rcpf(x); }
__device__ __forceinline__ float sigm(float x) { return frcp(1.0f + __expf(-x)); }

__global__ __launch_bounds__(BLK, 8) void crf_kernel(
    const float* __restrict__ logits, const float* __restrict__ p,
    float* __restrict__ out)
{
  const int lane  = threadIdx.x & 63;
  const int wid   = threadIdx.x >> 6;
  const int tile  = blockIdx.x * WPB + wid;     // global wave-tile id
  const int b     = tile / CPB;                 // compile-time-const divisor
  const int chunk = tile - b * CPB;
  const int s0    = chunk * C - HL;             // ext position 0 (mod 4 == 0)
  const int gb    = s0 + G * lane;              // own pos 0 (mod 4 == 0)
  const float* lg = logits + (size_t)b * N_;
  const float* pp = p + (size_t)b * N_ * 3;

  // interior: every index this tile touches is in [0, N) -> no clamps/masks
  const bool interior = (s0 >= 5) && (s0 + E + 5 < N_);

  // ---- own features (positions gb..gb+3) + unary: aligned float4 loads ----
  float own[12], un[G];
  if (interior) {
    const float4* vp = (const float4*)(pp + 3 * gb);   // 16B-aligned (gb%4==0)
    float4 v0 = vp[0], v1 = vp[1], v2 = vp[2];
    own[0] = v0.x; own[1]  = v0.y; own[2]  = v0.z; own[3]  = v0.w;
    own[4] = v1.x; own[5]  = v1.y; own[6]  = v1.z; own[7]  = v1.w;
    own[8] = v2.x; own[9]  = v2.y; own[10] = v2.z; own[11] = v2.w;
    float4 u = *(const float4*)(lg + gb);
    un[0] = u.x; un[1] = u.y; un[2] = u.z; un[3] = u.w;
  } else {
    #pragma unroll
    for (int k = 0; k < G; ++k) {
      int gc = min(max(gb + k, 0), N_ - 1);
      own[3 * k + 0] = pp[3 * (size_t)gc + 0];
      own[3 * k + 1] = pp[3 * (size_t)gc + 1];
      own[3 * k + 2] = pp[3 * (size_t)gc + 2];
      un[k] = lg[gc];
    }
  }

  // ---- right-halo features: positions gb+4..gb+8 (15 shuffles) ----
  float fh[5][3];
  #pragma unroll
  for (int j = 0; j < 4; ++j)
    #pragma unroll
    for (int c = 0; c < 3; ++c)
      fh[j][c] = __shfl_down(own[3 * j + c], 1);       // lane+1's pos j
  #pragma unroll
  for (int c = 0; c < 3; ++c)
    fh[4][c] = __shfl_down(own[c], 2);                 // lane+2's pos 0

  // ---- own-start upper weights: ww[k][d] = w(gb+k, gb+k+d+1), 20 exps ----
  float ww[G][5];
  #pragma unroll
  for (int k = 0; k < G; ++k) {
    #pragma unroll
    for (int d = 0; d < 5; ++d) {
      const int j = k + d + 1;                         // partner local idx 1..8
      float p0 = (j < 4) ? own[3 * j + 0] : fh[j - 4][0];
      float p1 = (j < 4) ? own[3 * j + 1] : fh[j - 4][1];
      float p2 = (j < 4) ? own[3 * j + 2] : fh[j - 4][2];
      float d0 = own[3 * k + 0] - p0;
      float d1 = own[3 * k + 1] - p1;
      float d2 = own[3 * k + 2] - p2;
      float ex = __expf(-0.5f * (d0 * d0 + d1 * d1 + d2 * d2));
      if (!interior)
        ex = (gb + k >= 0 && gb + k + d + 1 < N_) ? ex : 0.0f;
      ww[k][d] = ex;
    }
  }

  // ---- left weights by symmetry: wl[k][d] = w(gb+k-d-1 -> gb+k) ----
  float wl[G][5];
  #pragma unroll
  for (int k = 0; k < G; ++k) {
    #pragma unroll
    for (int d = 0; d < 5; ++d) {
      const int s = k - d - 1;                         // compile-time
      float v;
      if (s >= 0)       v = ww[s][d];
      else if (s >= -4) v = __shfl_up(ww[s + 4][d], 1);
      else              v = __shfl_up(ww[3][d], 2);
      wl[k][d] = v;
    }
  }

  // ---- normalize + q0 ----
  float q[G];
  #pragma unroll
  for (int k = 0; k < G; ++k) {
    float ws = EPS;
    #pragma unroll
    for (int d = 0; d < 5; ++d) ws += ww[k][d] + wl[k][d];
    float inv = frcp(ws);
    #pragma unroll
    for (int d = 0; d < 5; ++d) { ww[k][d] *= inv; wl[k][d] *= inv; }
    q[k] = sigm(un[k]);
  }

  // ---- 5 Jacobi iterations; q-halo via 10 shuffles, no LDS/barriers ----
  #pragma unroll
  for (int it = 0; it < NITER; ++it) {
    float qx[14];                        // q at ext position gb-5+j
    qx[0] = __shfl_up(q[3], 2);
    #pragma unroll
    for (int j = 0; j < 4; ++j) qx[1 + j] = __shfl_up(q[j], 1);
    #pragma unroll
    for (int k = 0; k < G; ++k) qx[5 + k] = q[k];
    #pragma unroll
    for (int j = 0; j < 4; ++j) qx[9 + j] = __shfl_down(q[j], 1);
    qx[13] = __shfl_down(q[0], 2);
    // lanes 0,1 / 62,63 get garbage halo; wrongness eroded within HL=28.

    #pragma unroll
    for (int k = 0; k < G; ++k) {
      float acc = un[k];                 // seed with unary: saves an add
      #pragma unroll
      for (int d = 0; d < 5; ++d) {
        acc += wl[k][d] * qx[5 + k - d - 1];
        acc += ww[k][d] * qx[5 + k + d + 1];
      }
      q[k] = sigm(acc);
    }
  }

  // ---- aligned float4 store of owned outputs (ext [HL, E-HL)) ----
  const int e0 = G * lane;
  if (e0 >= HL && e0 + G <= E - HL) {
    const int gx = chunk * C + (e0 - HL);
    float* ob = out + (size_t)b * N_ + gx;
    float4 v = make_float4(q[0], q[1], q[2], q[3]);
    if (gx + 3 < N_) {
      *(float4*)ob = v;
    } else {
      #pragma unroll
      for (int j = 0; j < 4; ++j)
        if (gx + j < N_) ob[j] = (&v.x)[j];
    }
  }
}

extern "C" void kernel_launch(void* const* d_in, const int* in_sizes, int n_in,
                              void* d_out, int out_size, void* d_ws, size_t ws_size,
                              hipStream_t stream) {
  const float* logits = (const float*)d_in[0];
  const float* p      = (const float*)d_in[1];
  float* out          = (float*)d_out;
  const int B = in_sizes[0] / N_;                // 16
  const int total_tiles = B * CPB;               // 8000
  dim3 grid(total_tiles / WPB), block(BLK);      // 2000 x 256
  crf_kernel<<<grid, block, 0, stream>>>(logits, p, out);
}

// Round 8
// 17.979 us; speedup vs baseline: 1.0233x; 1.0233x over previous
//
#include <hip/hip_runtime.h>

// CRF-RNN 1-D message passing. B=16, N=100000, K=11 (HALF=5), 5 iterations.
// One wave per block; each wave processes TWO independent tiles (w, w+4000)
// with both tiles' global loads issued up front (tile-B latency hides under
// tile-A compute). Per tile: thread owns G=4 consecutive positions; zero LDS,
// zero barriers — feature halo, weight symmetry, q-halo all via width-64
// shuffles; each unique Gaussian weight computed by exactly one lane.
// Edge tiles (2 per image) take a scalar clamped path with masks.

constexpr int BLK   = 64;            // one wave
constexpr int G     = 4;             // positions per thread
constexpr int E     = 64 * G;        // 256 ext positions per tile
constexpr int HL    = 28;            // halo each side (erosion-safe: 8 + 4*5)
constexpr int C     = E - 2 * HL;    // 200 outputs per tile (N = 500*200 exact)
constexpr int NITER = 5;
constexpr int N_    = 100000;
constexpr int CPB   = (N_ + C - 1) / C;   // 500 chunks per image
constexpr int TILES = 16 * CPB;           // 8000
constexpr int NWG   = TILES / 2;          // 4000 waves, 2 tiles each
constexpr float EPS = 1e-8f;

__device__ __forceinline__ float frcp(float x) { return __builtin_amdgcn_rcpf(x); }
__device__ __forceinline__ float sigm(float x) { return frcp(1.0f + __expf(-x)); }

__device__ __forceinline__ void load_tile(
    int tile, int lane,
    const float* __restrict__ logits, const float* __restrict__ p,
    float own[12], float un[4], int& gb, int& bb, int& chunk, bool& interior)
{
  bb    = tile / CPB;                  // const divisor -> magic multiply
  chunk = tile - bb * CPB;
  const int s0 = chunk * C - HL;       // ext position 0 (mod 4 == 0)
  gb = s0 + G * lane;                  // own pos 0 (mod 4 == 0)
  const float* lg = logits + (size_t)bb * N_;
  const float* pp = p + (size_t)bb * N_ * 3;
  interior = (s0 >= 5) && (s0 + E + 5 < N_);
  if (interior) {
    const float4* vp = (const float4*)(pp + 3 * gb);   // 16B-aligned
    float4 v0 = vp[0], v1 = vp[1], v2 = vp[2];
    own[0] = v0.x; own[1]  = v0.y; own[2]  = v0.z; own[3]  = v0.w;
    own[4] = v1.x; own[5]  = v1.y; own[6]  = v1.z; own[7]  = v1.w;
    own[8] = v2.x; own[9]  = v2.y; own[10] = v2.z; own[11] = v2.w;
    float4 u = *(const float4*)(lg + gb);
    un[0] = u.x; un[1] = u.y; un[2] = u.z; un[3] = u.w;
  } else {
    #pragma unroll
    for (int k = 0; k < G; ++k) {
      int gc = min(max(gb + k, 0), N_ - 1);
      own[3 * k + 0] = pp[3 * (size_t)gc + 0];
      own[3 * k + 1] = pp[3 * (size_t)gc + 1];
      own[3 * k + 2] = pp[3 * (size_t)gc + 2];
      un[k] = lg[gc];
    }
  }
}

__device__ __forceinline__ void process_tile(
    const float own[12], const float un[4],
    int gb, int bb, int chunk, bool interior, int lane,
    float* __restrict__ out)
{
  // ---- right-halo features: positions gb+4..gb+8 (15 shuffles) ----
  float fh[5][3];
  #pragma unroll
  for (int j = 0; j < 4; ++j)
    #pragma unroll
    for (int c = 0; c < 3; ++c)
      fh[j][c] = __shfl_down(own[3 * j + c], 1);       // lane+1's pos j
  #pragma unroll
  for (int c = 0; c < 3; ++c)
    fh[4][c] = __shfl_down(own[c], 2);                 // lane+2's pos 0

  // ---- own-start upper weights: ww[k][d] = w(gb+k, gb+k+d+1), 20 exps ----
  float ww[G][5];
  #pragma unroll
  for (int k = 0; k < G; ++k) {
    #pragma unroll
    for (int d = 0; d < 5; ++d) {
      const int j = k + d + 1;                         // partner local idx 1..8
      float p0 = (j < 4) ? own[3 * j + 0] : fh[j - 4][0];
      float p1 = (j < 4) ? own[3 * j + 1] : fh[j - 4][1];
      float p2 = (j < 4) ? own[3 * j + 2] : fh[j - 4][2];
      float d0 = own[3 * k + 0] - p0;
      float d1 = own[3 * k + 1] - p1;
      float d2 = own[3 * k + 2] - p2;
      float ex = __expf(-0.5f * (d0 * d0 + d1 * d1 + d2 * d2));
      if (!interior)
        ex = (gb + k >= 0 && gb + k + d + 1 < N_) ? ex : 0.0f;
      ww[k][d] = ex;
    }
  }

  // ---- left weights by symmetry: wl[k][d] = w(gb+k-d-1 -> gb+k) ----
  float wl[G][5];
  #pragma unroll
  for (int k = 0; k < G; ++k) {
    #pragma unroll
    for (int d = 0; d < 5; ++d) {
      const int s = k - d - 1;                         // compile-time
      float v;
      if (s >= 0)       v = ww[s][d];
      else if (s >= -4) v = __shfl_up(ww[s + 4][d], 1);
      else              v = __shfl_up(ww[3][d], 2);
      wl[k][d] = v;
    }
  }

  // ---- normalize + q0 ----
  float q[G];
  #pragma unroll
  for (int k = 0; k < G; ++k) {
    float ws = EPS;
    #pragma unroll
    for (int d = 0; d < 5; ++d) ws += ww[k][d] + wl[k][d];
    float inv = frcp(ws);
    #pragma unroll
    for (int d = 0; d < 5; ++d) { ww[k][d] *= inv; wl[k][d] *= inv; }
    q[k] = sigm(un[k]);
  }

  // ---- 5 Jacobi iterations; q-halo via 10 shuffles, no LDS/barriers ----
  #pragma unroll
  for (int it = 0; it < NITER; ++it) {
    float qx[14];                        // q at ext position gb-5+j
    qx[0] = __shfl_up(q[3], 2);
    #pragma unroll
    for (int j = 0; j < 4; ++j) qx[1 + j] = __shfl_up(q[j], 1);
    #pragma unroll
    for (int k = 0; k < G; ++k) qx[5 + k] = q[k];
    #pragma unroll
    for (int j = 0; j < 4; ++j) qx[9 + j] = __shfl_down(q[j], 1);
    qx[13] = __shfl_down(q[0], 2);
    // lanes 0,1 / 62,63 get garbage halo; wrongness eroded within HL=28.

    #pragma unroll
    for (int k = 0; k < G; ++k) {
      float acc = un[k];
      #pragma unroll
      for (int d = 0; d < 5; ++d) {
        acc += wl[k][d] * qx[5 + k - d - 1];
        acc += ww[k][d] * qx[5 + k + d + 1];
      }
      q[k] = sigm(acc);
    }
  }

  // ---- aligned float4 store of owned outputs (ext [HL, E-HL)) ----
  const int e0 = G * lane;
  if (e0 >= HL && e0 + G <= E - HL) {
    const int gx = chunk * C + (e0 - HL);
    float* ob = out + (size_t)bb * N_ + gx;
    float4 v = make_float4(q[0], q[1], q[2], q[3]);
    if (gx + 3 < N_) {
      *(float4*)ob = v;
    } else {
      #pragma unroll
      for (int j = 0; j < 4; ++j)
        if (gx + j < N_) ob[j] = (&v.x)[j];
    }
  }
}

__global__ __launch_bounds__(BLK, 4) void crf_kernel(
    const float* __restrict__ logits, const float* __restrict__ p,
    float* __restrict__ out)
{
  const int lane = threadIdx.x;
  const int tA   = blockIdx.x;            // first tile
  const int tB   = blockIdx.x + NWG;      // second tile

  float ownA[12], unA[4], ownB[12], unB[4];
  int gbA, bA, chA, gbB, bB, chB;
  bool intA, intB;

  // issue ALL global loads up front; tile-B latency hides under tile-A compute
  load_tile(tA, lane, logits, p, ownA, unA, gbA, bA, chA, intA);
  load_tile(tB, lane, logits, p, ownB, unB, gbB, bB, chB, intB);

  process_tile(ownA, unA, gbA, bA, chA, intA, lane, out);
  process_tile(ownB, unB, gbB, bB, chB, intB, lane, out);
}

extern "C" void kernel_launch(void* const* d_in, const int* in_sizes, int n_in,
                              void* d_out, int out_size, void* d_ws, size_t ws_size,
                              hipStream_t stream) {
  const float* logits = (const float*)d_in[0];
  const float* p      = (const float*)d_in[1];
  float* out          = (float*)d_out;
  dim3 grid(NWG), block(BLK);             // 4000 x 64
  crf_kernel<<<grid, block, 0, stream>>>(logits, p, out);
}

// Round 9
// 16.688 us; speedup vs baseline: 1.1024x; 1.0773x over previous
//
#include <hip/hip_runtime.h>

// CRF-RNN 1-D message passing. B=16, N=100000, K=11 (HALF=5), 5 iterations.
// Best-measured configuration (R6 structure): one wave per block, thread owns
// G=4 consecutive positions. Zero LDS, zero barriers: feature halo, weight
// symmetry sharing, and per-iteration q-halo all via width-64 wave shuffles.
// Each unique Gaussian weight computed by exactly one lane (20 exps/thread);
// left weights via shfl_up of unnormalized ww. Edge tiles (2 per image) take
// a scalar clamped path with masks.
// Session ledger: R1 32.7 / R2 18.9 / R3 23.3 / R4 33.7 / R5 19.0 / R6 16.9 /
// R7 18.4 / R8 18.0 µs. Counters (R7): VALUBusy 2%, HBM 3%, Occ 1.8% ->
// latency/launch-floor regime; this config is the measured optimum.

constexpr int BLK   = 64;            // one wave
constexpr int G     = 4;             // positions per thread
constexpr int E     = 64 * G;        // 256 ext positions per tile
constexpr int HL    = 28;            // halo each side (erosion-safe: 8 + 4*5)
constexpr int C     = E - 2 * HL;    // 200 outputs per tile (N = 500*200 exact)
constexpr int NITER = 5;
constexpr int N_    = 100000;
constexpr int CPB   = (N_ + C - 1) / C;   // 500 chunks per image
constexpr float EPS = 1e-8f;

__device__ __forceinline__ float frcp(float x) { return __builtin_amdgcn_rcpf(x); }
__device__ __forceinline__ float sigm(float x) { return frcp(1.0f + __expf(-x)); }

__global__ __launch_bounds__(BLK, 4) void crf_kernel(
    const float* __restrict__ logits, const float* __restrict__ p,
    float* __restrict__ out)
{
  const int lane  = threadIdx.x;
  const int b     = blockIdx.x / CPB;           // const divisor -> magic mul
  const int chunk = blockIdx.x - b * CPB;
  const int s0    = chunk * C - HL;             // ext position 0 (mod 4 == 0)
  const int gb    = s0 + G * lane;              // own pos 0 (mod 4 == 0)
  const float* lg = logits + (size_t)b * N_;
  const float* pp = p + (size_t)b * N_ * 3;

  // interior: every index this tile touches is in [0, N) -> no clamps/masks
  const bool interior = (s0 >= 5) && (s0 + E + 5 < N_);

  // ---- own features (positions gb..gb+3) + unary: aligned float4 loads ----
  float own[12], un[G];
  if (interior) {
    const float4* vp = (const float4*)(pp + 3 * gb);   // 16B-aligned (gb%4==0)
    float4 v0 = vp[0], v1 = vp[1], v2 = vp[2];
    own[0] = v0.x; own[1]  = v0.y; own[2]  = v0.z; own[3]  = v0.w;
    own[4] = v1.x; own[5]  = v1.y; own[6]  = v1.z; own[7]  = v1.w;
    own[8] = v2.x; own[9]  = v2.y; own[10] = v2.z; own[11] = v2.w;
    float4 u = *(const float4*)(lg + gb);
    un[0] = u.x; un[1] = u.y; un[2] = u.z; un[3] = u.w;
  } else {
    #pragma unroll
    for (int k = 0; k < G; ++k) {
      int gc = min(max(gb + k, 0), N_ - 1);
      own[3 * k + 0] = pp[3 * (size_t)gc + 0];
      own[3 * k + 1] = pp[3 * (size_t)gc + 1];
      own[3 * k + 2] = pp[3 * (size_t)gc + 2];
      un[k] = lg[gc];
    }
  }

  // ---- right-halo features: positions gb+4..gb+8 (15 shuffles) ----
  float fh[5][3];
  #pragma unroll
  for (int j = 0; j < 4; ++j)
    #pragma unroll
    for (int c = 0; c < 3; ++c)
      fh[j][c] = __shfl_down(own[3 * j + c], 1);       // lane+1's pos j
  #pragma unroll
  for (int c = 0; c < 3; ++c)
    fh[4][c] = __shfl_down(own[c], 2);                 // lane+2's pos 0

  // ---- own-start upper weights: ww[k][d] = w(gb+k, gb+k+d+1), 20 exps ----
  float ww[G][5];
  #pragma unroll
  for (int k = 0; k < G; ++k) {
    #pragma unroll
    for (int d = 0; d < 5; ++d) {
      const int j = k + d + 1;                         // partner local idx 1..8
      float p0 = (j < 4) ? own[3 * j + 0] : fh[j - 4][0];
      float p1 = (j < 4) ? own[3 * j + 1] : fh[j - 4][1];
      float p2 = (j < 4) ? own[3 * j + 2] : fh[j - 4][2];
      float d0 = own[3 * k + 0] - p0;
      float d1 = own[3 * k + 1] - p1;
      float d2 = own[3 * k + 2] - p2;
      float ex = __expf(-0.5f * (d0 * d0 + d1 * d1 + d2 * d2));
      if (!interior)
        ex = (gb + k >= 0 && gb + k + d + 1 < N_) ? ex : 0.0f;
      ww[k][d] = ex;
    }
  }

  // ---- left weights by symmetry: wl[k][d] = w(gb+k-d-1 -> gb+k) ----
  float wl[G][5];
  #pragma unroll
  for (int k = 0; k < G; ++k) {
    #pragma unroll
    for (int d = 0; d < 5; ++d) {
      const int s = k - d - 1;                         // compile-time
      float v;
      if (s >= 0)       v = ww[s][d];
      else if (s >= -4) v = __shfl_up(ww[s + 4][d], 1);
      else              v = __shfl_up(ww[3][d], 2);
      wl[k][d] = v;
    }
  }

  // ---- normalize + q0 ----
  float q[G];
  #pragma unroll
  for (int k = 0; k < G; ++k) {
    float ws = EPS;
    #pragma unroll
    for (int d = 0; d < 5; ++d) ws += ww[k][d] + wl[k][d];
    float inv = frcp(ws);
    #pragma unroll
    for (int d = 0; d < 5; ++d) { ww[k][d] *= inv; wl[k][d] *= inv; }
    q[k] = sigm(un[k]);
  }

  // ---- 5 Jacobi iterations; q-halo via 10 shuffles, no LDS/barriers ----
  #pragma unroll
  for (int it = 0; it < NITER; ++it) {
    float qx[14];                        // q at ext position gb-5+j
    qx[0] = __shfl_up(q[3], 2);
    #pragma unroll
    for (int j = 0; j < 4; ++j) qx[1 + j] = __shfl_up(q[j], 1);
    #pragma unroll
    for (int k = 0; k < G; ++k) qx[5 + k] = q[k];
    #pragma unroll
    for (int j = 0; j < 4; ++j) qx[9 + j] = __shfl_down(q[j], 1);
    qx[13] = __shfl_down(q[0], 2);
    // lanes 0,1 / 62,63 get garbage halo; wrongness eroded within HL=28.

    #pragma unroll
    for (int k = 0; k < G; ++k) {
      float acc = un[k];                 // seed with unary
      #pragma unroll
      for (int d = 0; d < 5; ++d) {
        acc += wl[k][d] * qx[5 + k - d - 1];
        acc += ww[k][d] * qx[5 + k + d + 1];
      }
      q[k] = sigm(acc);
    }
  }

  // ---- aligned float4 store of owned outputs (ext [HL, E-HL)) ----
  const int e0 = G * lane;
  if (e0 >= HL && e0 + G <= E - HL) {
    const int gx = chunk * C + (e0 - HL);
    float* ob = out + (size_t)b * N_ + gx;
    float4 v = make_float4(q[0], q[1], q[2], q[3]);
    if (gx + 3 < N_) {
      *(float4*)ob = v;
    } else {
      #pragma unroll
      for (int j = 0; j < 4; ++j)
        if (gx + j < N_) ob[j] = (&v.x)[j];
    }
  }
}

extern "C" void kernel_launch(void* const* d_in, const int* in_sizes, int n_in,
                              void* d_out, int out_size, void* d_ws, size_t ws_size,
                              hipStream_t stream) {
  const float* logits = (const float*)d_in[0];
  const float* p      = (const float*)d_in[1];
  float* out          = (float*)d_out;
  const int B = in_sizes[0] / N_;                // 16
  dim3 grid(B * CPB), block(BLK);                // 8000 x 64
  crf_kernel<<<grid, block, 0, stream>>>(logits, p, out);
}